// Round 15
// baseline (237.001 us; speedup 1.0000x reference)
//
#include <hip/hip_runtime.h>
#include <math.h>

#define TB   256
#define HH   128     // input H=W
#define OHW  64      // output H=W
#define TR   16      // output rows per tile (4 tiles/plane)
#define N0C  68      // n0 row stride; out col c at index c+2
#define NBLK (16 * 256 * 4)
#define CPX  (NBLK / 8)     // blocks per XCD chunk

typedef float f32x2 __attribute__((ext_vector_type(2)));

__device__ __forceinline__ float sigmoidf(float z) {
    return 1.0f / (1.0f + __expf(-z));
}

// No x staging: each thread reads its 5x5 input window straight from global
// (6 float4 + 6 scalar independent loads; L1/L2 serve the 3x vertical reuse).
// Only n0 goes through LDS (4.9 KB) -> 8 blocks/CU = 32 waves, loads stream
// continuously instead of stage-burst/barrier-drain/compute phase-lock.
__global__ __launch_bounds__(TB, 8) void fused_densenet_kernel(
    const float* __restrict__ x,
    const float* __restrict__ maxgate,
    const float* __restrict__ mb,
    const float* __restrict__ pconvs,
    const float* __restrict__ pbs,
    const float* __restrict__ pgates,
    const float* __restrict__ gbs,
    float* __restrict__ out)
{
    __shared__ float n0s[TR + 2][N0C];    // n0 with 1-halo (4.9 KB)

    const int t     = threadIdx.x;
    const int bid   = blockIdx.x;
    const int l     = (bid & 7) * CPX + (bid >> 3);   // bijective XCD swizzle
    const int tile  = l & 3;
    const int plane = l >> 2;             // b*256 + c
    const int c     = plane & 255;
    const int r0    = tile * TR;
    const int p     = t & 31;             // col pair: out cols {2p, 2p+1}
    const int q     = t >> 5;             // row pair 0..7: out rows {2q, 2q+1}

    // ---- weights/biases (block-uniform address -> SGPR-resident) ----
    // ws rows: 0=maxgate 1=p0 2=p1 3=p2 4=p3 5=gate0 6=gate2(leaf1+node)
    float ws[7][9];
#pragma unroll
    for (int i = 0; i < 9; ++i) {
        ws[0][i] = maxgate[c * 9  + i];
        ws[1][i] = pconvs [c * 36 + i * 4 + 0];
        ws[2][i] = pconvs [c * 36 + i * 4 + 1];
        ws[3][i] = pconvs [c * 36 + i * 4 + 2];
        ws[4][i] = pconvs [c * 36 + i * 4 + 3];
        ws[5][i] = pgates [c * 27 + i * 3 + 0];
        ws[6][i] = pgates [c * 27 + i * 3 + 2];
    }
    const float bmax = mb[c];
    const float bp0 = pbs[c * 4 + 0], bp1 = pbs[c * 4 + 1];
    const float bp2 = pbs[c * 4 + 2], bp3 = pbs[c * 4 + 3];
    const float bg0 = gbs[c * 3 + 0];   // leaf0 gate bias
    const float bg1 = gbs[c * 3 + 1];   // leaf1 gate bias
    const float bg2 = gbs[c * 3 + 2];   // node gate bias

    const float* xplane = x + (size_t)plane * (HH * HH);

    // n0 side cols (out cols -1 / 64 are outside the image -> 0)
    if (t < 2 * (TR + 2)) n0s[t >> 1][(t & 1) ? 66 : 1] = 0.f;

    // ---- n0 halo rows (gr = r0-1, r0+TR), direct from global ----
    if (t < 132) {
        const int hb  = (t >= 66);
        const int cc2 = hb ? t - 66 : t;           // 0..65
        const int gc  = cc2 - 1;                   // out col -1..64
        const int gr  = hb ? r0 + TR : r0 - 1;
        float n0v = 0.f;
        if ((unsigned)gr < (unsigned)OHW && (unsigned)gc < (unsigned)OHW) {
            float ag = 0.f, a0 = 0.f, a1 = 0.f;
#pragma unroll
            for (int dr = 0; dr < 3; ++dr) {
                const int ir = 2 * gr - 1 + dr;
                if (ir >= 0) {                     // only gr==0,dr==0 fails
                    const float* row = xplane + ir * HH;
                    const float w0 = (gc > 0) ? row[2 * gc - 1] : 0.f;
                    const f32x2 d  = *reinterpret_cast<const f32x2*>(&row[2 * gc]);
                    ag += w0 * ws[5][3*dr] + d.x * ws[5][3*dr+1] + d.y * ws[5][3*dr+2];
                    a0 += w0 * ws[1][3*dr] + d.x * ws[1][3*dr+1] + d.y * ws[1][3*dr+2];
                    a1 += w0 * ws[2][3*dr] + d.x * ws[2][3*dr+1] + d.y * ws[2][3*dr+2];
                }
            }
            const float sg = sigmoidf(ag + bg0);
            n0v = sg * (a0 + bp0) + (1.f - sg) * (a1 + bp1);
        }
        n0s[hb ? TR + 1 : 0][cc2 + 1] = n0v;
    }

    // ---- interior: 2 rows x 2 cols per thread, direct-global 5x5 window ----
    float out1[2][2], n1v[2][2];
#pragma unroll
    for (int k = 0; k < 2; ++k) {
        const int lr = 2 * q + k;
        const int gr = r0 + lr;
        float a[7][2];
#pragma unroll
        for (int ci = 0; ci < 7; ++ci) { a[ci][0] = 0.f; a[ci][1] = 0.f; }
        float mp0 = -INFINITY, mp1 = -INFINITY;
#pragma unroll
        for (int dr = 0; dr < 3; ++dr) {
            const int ir = 2 * gr - 1 + dr;        // <0 only for gr==0,dr==0
            const bool rok = (ir >= 0);
            const float* row = xplane + ir * HH;
            float  v0 = 0.f;
            float4 vv = make_float4(0.f, 0.f, 0.f, 0.f);
            if (rok) {
                if (p > 0) v0 = row[4 * p - 1];
                vv = *reinterpret_cast<const float4*>(&row[4 * p]);
            }
            const float h0 = fmaxf(fmaxf((p > 0) ? v0 : -INFINITY, vv.x), vv.y);
            const float h1 = fmaxf(fmaxf(vv.y, vv.z), vv.w);
            mp0 = fmaxf(mp0, rok ? h0 : -INFINITY);
            mp1 = fmaxf(mp1, rok ? h1 : -INFINITY);
#pragma unroll
            for (int ci = 0; ci < 7; ++ci) {
                a[ci][0] += v0   * ws[ci][3*dr] + vv.x * ws[ci][3*dr+1] + vv.y * ws[ci][3*dr+2];
                a[ci][1] += vv.y * ws[ci][3*dr] + vv.z * ws[ci][3*dr+1] + vv.w * ws[ci][3*dr+2];
            }
        }
        const float sg0a = sigmoidf(a[5][0] + bg0);
        const float sg0b = sigmoidf(a[5][1] + bg0);
        const float n0a = sg0a * (a[1][0] + bp0) + (1.f - sg0a) * (a[2][0] + bp1);
        const float n0b = sg0b * (a[1][1] + bp0) + (1.f - sg0b) * (a[2][1] + bp1);
        *reinterpret_cast<f32x2*>(&n0s[lr + 1][2 * p + 2]) = (f32x2){ n0a, n0b };
        const float sg1a = sigmoidf(a[6][0] + bg1);    // leaf1 gate: bias gbs[:,1]
        const float sg1b = sigmoidf(a[6][1] + bg1);
        n1v[k][0] = sg1a * (a[3][0] + bp2) + (1.f - sg1a) * (a[4][0] + bp3);
        n1v[k][1] = sg1b * (a[3][1] + bp2) + (1.f - sg1b) * (a[4][1] + bp3);
        out1[k][0] = mp0 * (a[0][0] + bmax);
        out1[k][1] = mp1 * (a[0][1] + bmax);
    }
    __syncthreads();    // the only barrier: n0 exchange

    // ---- stage 2: node gate conv on n0 (stride 1, pad 1) + combine + store ----
    float* oplane = out + (size_t)plane * (OHW * OHW);
#pragma unroll
    for (int k = 0; k < 2; ++k) {
        const int lr = 2 * q + k;
        float ag0 = 0.f, ag1 = 0.f, n0c0 = 0.f, n0c1 = 0.f;
#pragma unroll
        for (int dr = 0; dr < 3; ++dr) {
            const float e0  = n0s[lr + dr][2 * p + 1];
            const f32x2 mid = *reinterpret_cast<const f32x2*>(&n0s[lr + dr][2 * p + 2]);
            const float e3  = n0s[lr + dr][2 * p + 4];
            ag0 += e0    * ws[6][3*dr] + mid.x * ws[6][3*dr+1] + mid.y * ws[6][3*dr+2];
            ag1 += mid.x * ws[6][3*dr] + mid.y * ws[6][3*dr+1] + e3    * ws[6][3*dr+2];
            if (dr == 1) { n0c0 = mid.x; n0c1 = mid.y; }
        }
        const float ga = sigmoidf(ag0 + bg2);          // node gate: bias gbs[:,2]
        const float gb = sigmoidf(ag1 + bg2);
        f32x2 rv;
        rv.x = out1[k][0] + n0c0 * ga + n1v[k][0] * (1.f - ga);
        rv.y = out1[k][1] + n0c1 * gb + n1v[k][1] * (1.f - gb);
        __builtin_nontemporal_store(rv,
            reinterpret_cast<f32x2*>(oplane + (r0 + lr) * OHW + 2 * p));
    }
}

extern "C" void kernel_launch(void* const* d_in, const int* in_sizes, int n_in,
                              void* d_out, int out_size, void* d_ws, size_t ws_size,
                              hipStream_t stream) {
    const float* x       = (const float*)d_in[0];
    const float* maxgate = (const float*)d_in[1];
    const float* mb      = (const float*)d_in[2];
    const float* pconvs  = (const float*)d_in[3];
    const float* pbs     = (const float*)d_in[4];
    const float* pgates  = (const float*)d_in[5];
    const float* gbs     = (const float*)d_in[6];
    float* out           = (float*)d_out;

    fused_densenet_kernel<<<NBLK, TB, 0, stream>>>(
        x, maxgate, mb, pconvs, pbs, pgates, gbs, out);
}

// Round 16
// 81.450 us; speedup vs baseline: 2.9098x; 2.9098x over previous
//
#include <hip/hip_runtime.h>
#include <math.h>

#define TB   256
#define HH   128     // input H=W
#define OHW  64      // output H=W
#define TR   16      // output rows per tile (4 tiles/plane)
#define XR   37      // slab rows: 2*TR+5
#define N0C  68      // n0 row stride; out col c at index c+2
#define NBLK (16 * 256 * 4)
#define CPX  (NBLK / 8)     // blocks per XCD chunk

typedef float f32x2 __attribute__((ext_vector_type(2)));

__device__ __forceinline__ float sigmoidf(float z) {
    return 1.0f / (1.0f + __expf(-z));
}

__device__ __forceinline__ void gl2lds16(const float* g, float* l) {
    __builtin_amdgcn_global_load_lds(
        (const __attribute__((address_space(1))) void*)g,
        (__attribute__((address_space(3))) void*)l, 16, 0, 0);
}
__device__ __forceinline__ void gl2lds4(const float* g, float* l) {
    __builtin_amdgcn_global_load_lds(
        (const __attribute__((address_space(1))) void*)g,
        (__attribute__((address_space(3))) void*)l, 4, 0, 0);
}

// R13 champion + packed-f32 (VOP3P v_pk_fma_f32 / v_pk_max_f32) interior:
// accumulate both output cols of a thread as one f32x2 -> ~half the VALU
// instructions in the conv core. Structure/staging byte-identical to R13.
__global__ __launch_bounds__(TB, 6) void fused_densenet_kernel(
    const float* __restrict__ x,
    const float* __restrict__ maxgate,
    const float* __restrict__ mb,
    const float* __restrict__ pconvs,
    const float* __restrict__ pbs,
    const float* __restrict__ pgates,
    const float* __restrict__ gbs,
    float* __restrict__ out)
{
    __shared__ float xs[XR][HH];          // contiguous slab (18.5 KB)
    __shared__ float n0s[TR + 2][N0C];    // n0 with 1-halo (4.9 KB)

    const int t     = threadIdx.x;
    const int lane  = t & 63;
    const int wv    = t >> 6;             // wave 0..3
    const int bid   = blockIdx.x;
    const int l     = (bid & 7) * CPX + (bid >> 3);   // bijective XCD swizzle
    const int tile  = l & 3;
    const int plane = l >> 2;             // b*256 + c
    const int c     = plane & 255;
    const int r0    = tile * TR;

    // ---- weights/biases (block-uniform address -> SGPR-resident) ----
    // ws rows: 0=maxgate 1=p0 2=p1 3=p2 4=p3 5=gate0 6=gate2(leaf1+node)
    float ws[7][9];
#pragma unroll
    for (int i = 0; i < 9; ++i) {
        ws[0][i] = maxgate[c * 9  + i];
        ws[1][i] = pconvs [c * 36 + i * 4 + 0];
        ws[2][i] = pconvs [c * 36 + i * 4 + 1];
        ws[3][i] = pconvs [c * 36 + i * 4 + 2];
        ws[4][i] = pconvs [c * 36 + i * 4 + 3];
        ws[5][i] = pgates [c * 27 + i * 3 + 0];
        ws[6][i] = pgates [c * 27 + i * 3 + 2];
    }
    const float bmax = mb[c];
    const float bp0 = pbs[c * 4 + 0], bp1 = pbs[c * 4 + 1];
    const float bp2 = pbs[c * 4 + 2], bp3 = pbs[c * 4 + 3];
    const float bg0 = gbs[c * 3 + 0];   // leaf0 gate bias
    const float bg1 = gbs[c * 3 + 1];   // leaf1 gate bias
    const float bg2 = gbs[c * 3 + 2];   // node gate bias

    const float* xplane = x + (size_t)plane * (HH * HH);

    // ---- async stage: input rows 2r0-3 .. 2r0+33 into xs, zero-pad at edges ----
    {
        const int ir0  = 2 * r0 - 3;
        const int lo   = ir0 < 0 ? 0 : ir0;
        const int hie  = ir0 + XR - 1;
        const int hi   = hie > HH - 1 ? HH - 1 : hie;
        const int ztop = lo - ir0;                 // 3 for tile 0, else 0
        const int zbot = hie - hi;                 // 2 for tile 3, else 0
        for (int i = t; i < ztop * HH; i += TB) (&xs[0][0])[i] = 0.f;
        for (int i = t; i < zbot * HH; i += TB) (&xs[XR - zbot][0])[i] = 0.f;
        const int    nfl  = (hi - lo + 1) * HH;    // multiple of 128
        const float* gsrc = xplane + lo * HH;
        float*       ldst = &xs[ztop][0];
        const int nchunk = nfl >> 8;               // 1KB chunks (64 lanes x 16B)
        for (int k = wv; k < nchunk; k += TB / 64)
            gl2lds16(gsrc + (k << 8) + lane * 4, ldst + (k << 8));
        if ((nfl & 255) && wv == 0) {              // 512B tail
            const int off = nchunk << 8;
            gl2lds4(gsrc + off + lane,      ldst + off);
            gl2lds4(gsrc + off + 64 + lane, ldst + off + 64);
        }
        // n0 side cols (gc = -1 and 64) are outside the image -> always 0
        if (t < 2 * (TR + 2)) n0s[t >> 1][(t & 1) ? 66 : 1] = 0.f;
    }
    __syncthreads();                               // slab + side zeros ready

    // ---- n0 halo rows (gr = r0-1, r0+TR; zero outside image) ----
    if (t < 132) {
        const int hb  = (t >= 66);                 // 0 top, 1 bottom
        const int cc2 = hb ? t - 66 : t;           // 0..65
        const int gc  = cc2 - 1;                   // out col -1..64
        const int gr  = hb ? r0 + TR : r0 - 1;
        float n0v = 0.f;
        if ((unsigned)gr < (unsigned)OHW && (unsigned)gc < (unsigned)OHW) {
            const int sb = hb ? 2 * TR + 2 : 0;    // slab row base
            float ag = 0.f, a0 = 0.f, a1 = 0.f;
#pragma unroll
            for (int dr = 0; dr < 3; ++dr) {
                const float* row = &xs[sb + dr][0];
                const float w0 = (gc > 0) ? row[2 * gc - 1] : 0.f;
                const float w1 = row[2 * gc];
                const float w2 = row[2 * gc + 1];
                ag += w0 * ws[5][3*dr] + w1 * ws[5][3*dr+1] + w2 * ws[5][3*dr+2];
                a0 += w0 * ws[1][3*dr] + w1 * ws[1][3*dr+1] + w2 * ws[1][3*dr+2];
                a1 += w0 * ws[2][3*dr] + w1 * ws[2][3*dr+1] + w2 * ws[2][3*dr+2];
            }
            const float sg = sigmoidf(ag + bg0);
            n0v = sg * (a0 + bp0) + (1.f - sg) * (a1 + bp1);
        }
        n0s[hb ? TR + 1 : 0][cc2 + 1] = n0v;
    }

    // ---- stage 1 interior: 2 cols x 1 row per micro-step, packed f32x2 ----
    const int p  = t & 31;             // col pair: out cols {2p, 2p+1}
    const int g0 = t >> 5;             // 0..7
    f32x2 out1[2], n1v[2];
    const f32x2 NEGI = (f32x2){ -INFINITY, -INFINITY };

#pragma unroll
    for (int k = 0; k < 2; ++k) {
        const int lr = g0 + 8 * k;
        const int gr = r0 + lr;
        f32x2 acc[7];
#pragma unroll
        for (int ci = 0; ci < 7; ++ci) acc[ci] = (f32x2){ 0.f, 0.f };
        f32x2 mpp = NEGI;
#pragma unroll
        for (int dr = 0; dr < 3; ++dr) {
            const float* row = &xs[2 * lr + 2 + dr][0];
            const float  v0 = (p > 0) ? row[4 * p - 1] : 0.f;
            const float4 vv = *reinterpret_cast<const float4*>(&row[4 * p]);
            const f32x2 s0 = (f32x2){ v0,   vv.y };
            const f32x2 s1 = (f32x2){ vv.x, vv.z };
            const f32x2 s2 = (f32x2){ vv.y, vv.w };
            // maxpool (pad = -inf): left col invalid at p==0, row at gr==0,dr==0
            const f32x2 m0 = (f32x2){ (p > 0) ? v0 : -INFINITY, vv.y };
            const f32x2 hh = __builtin_elementwise_max(
                                 __builtin_elementwise_max(m0, s1), s2);
            const bool rowok = (gr > 0) | (dr > 0);
            mpp = __builtin_elementwise_max(mpp, rowok ? hh : NEGI);
#pragma unroll
            for (int ci = 0; ci < 7; ++ci)
                acc[ci] += s0 * ws[ci][3*dr] + s1 * ws[ci][3*dr+1] + s2 * ws[ci][3*dr+2];
        }
        const float sg0a = sigmoidf(acc[5].x + bg0);
        const float sg0b = sigmoidf(acc[5].y + bg0);
        const float n0a = sg0a * (acc[1].x + bp0) + (1.f - sg0a) * (acc[2].x + bp1);
        const float n0b = sg0b * (acc[1].y + bp0) + (1.f - sg0b) * (acc[2].y + bp1);
        *reinterpret_cast<f32x2*>(&n0s[lr + 1][2 * p + 2]) = (f32x2){ n0a, n0b };
        const float sg1a = sigmoidf(acc[6].x + bg1);   // leaf1 gate: bias gbs[:,1]
        const float sg1b = sigmoidf(acc[6].y + bg1);
        n1v[k] = (f32x2){ sg1a * (acc[3].x + bp2) + (1.f - sg1a) * (acc[4].x + bp3),
                          sg1b * (acc[3].y + bp2) + (1.f - sg1b) * (acc[4].y + bp3) };
        out1[k] = mpp * (acc[0] + (f32x2){ bmax, bmax });
    }
    __syncthreads();

    // ---- stage 2: node gate conv on n0 (stride 1, pad 1), packed + store ----
    float* oplane = out + (size_t)plane * (OHW * OHW);
#pragma unroll
    for (int k = 0; k < 2; ++k) {
        const int lr = g0 + 8 * k;
        f32x2 agp = (f32x2){ 0.f, 0.f };
        f32x2 n0c = (f32x2){ 0.f, 0.f };
#pragma unroll
        for (int dr = 0; dr < 3; ++dr) {
            const float e0  = n0s[lr + dr][2 * p + 1];
            const f32x2 mid = *reinterpret_cast<const f32x2*>(&n0s[lr + dr][2 * p + 2]);
            const float e3  = n0s[lr + dr][2 * p + 4];
            const f32x2 s0 = (f32x2){ e0,    mid.x };
            const f32x2 s2 = (f32x2){ mid.y, e3    };
            agp += s0 * ws[6][3*dr] + mid * ws[6][3*dr+1] + s2 * ws[6][3*dr+2];
            if (dr == 1) n0c = mid;
        }
        const float ga = sigmoidf(agp.x + bg2);        // node gate: bias gbs[:,2]
        const float gb = sigmoidf(agp.y + bg2);
        const f32x2 g  = (f32x2){ ga, gb };
        const f32x2 rv = out1[k] + n0c * g + n1v[k] * ((f32x2){1.f,1.f} - g);
        __builtin_nontemporal_store(rv,
            reinterpret_cast<f32x2*>(oplane + (r0 + lr) * OHW + 2 * p));
    }
}

extern "C" void kernel_launch(void* const* d_in, const int* in_sizes, int n_in,
                              void* d_out, int out_size, void* d_ws, size_t ws_size,
                              hipStream_t stream) {
    const float* x       = (const float*)d_in[0];
    const float* maxgate = (const float*)d_in[1];
    const float* mb      = (const float*)d_in[2];
    const float* pconvs  = (const float*)d_in[3];
    const float* pbs     = (const float*)d_in[4];
    const float* pgates  = (const float*)d_in[5];
    const float* gbs     = (const float*)d_in[6];
    float* out           = (float*)d_out;

    fused_densenet_kernel<<<NBLK, TB, 0, stream>>>(
        x, maxgate, mb, pconvs, pbs, pgates, gbs, out);
}

// Round 17
// 80.552 us; speedup vs baseline: 2.9422x; 1.0112x over previous
//
#include <hip/hip_runtime.h>
#include <math.h>

#define TB   256
#define HH   128     // input H=W
#define OHW  64      // output H=W
#define TR   16      // output rows per tile (4 tiles/plane)
#define XR   37      // slab rows: 2*TR+5
#define N0C  68      // n0 row stride; out col c at index c+2
#define NBLK (16 * 256 * 4)
#define CPX  (NBLK / 8)     // blocks per XCD chunk

typedef float f32x2 __attribute__((ext_vector_type(2)));

__device__ __forceinline__ float sigmoidf(float z) {
    return 1.0f / (1.0f + __expf(-z));
}

__device__ __forceinline__ void gl2lds16(const float* g, float* l) {
    __builtin_amdgcn_global_load_lds(
        (const __attribute__((address_space(1))) void*)g,
        (__attribute__((address_space(3))) void*)l, 16, 0, 0);
}
__device__ __forceinline__ void gl2lds4(const float* g, float* l) {
    __builtin_amdgcn_global_load_lds(
        (const __attribute__((address_space(1))) void*)g,
        (__attribute__((address_space(3))) void*)l, 4, 0, 0);
}

// R13 champion + initial-cohort stagger: blocks 0..255 hit each CU once, so
// cohort k = bid>>8. The first 6 cohorts are co-resident and phase-locked
// (stage together -> barrier -> compute together, memory and VALU alternate
// idle). Sleeping cohort k for k x ~1980 cycles desynchronizes the resident
// blocks once; completion->relaunch inherits the offset, so one block's
// staging overlaps the others' compute for the rest of the kernel.
__global__ __launch_bounds__(TB, 6) void fused_densenet_kernel(
    const float* __restrict__ x,
    const float* __restrict__ maxgate,
    const float* __restrict__ mb,
    const float* __restrict__ pconvs,
    const float* __restrict__ pbs,
    const float* __restrict__ pgates,
    const float* __restrict__ gbs,
    float* __restrict__ out)
{
    __shared__ float xs[XR][HH];          // contiguous slab (18.5 KB)
    __shared__ float n0s[TR + 2][N0C];    // n0 with 1-halo (4.9 KB)

    const int t     = threadIdx.x;
    const int lane  = t & 63;
    const int wv    = t >> 6;             // wave 0..3
    const int bid   = blockIdx.x;

    // ---- desync sleep (perf heuristic only; no effect on results) ----
    {
        const int gen = bid >> 8;         // per-CU cohort index at startup
        if (gen >= 1 && gen < 6) {
#pragma unroll 1
            for (int i = 0; i < gen; ++i) __builtin_amdgcn_s_sleep(31);
        }
    }

    const int l     = (bid & 7) * CPX + (bid >> 3);   // bijective XCD swizzle
    const int tile  = l & 3;
    const int plane = l >> 2;             // b*256 + c
    const int c     = plane & 255;
    const int r0    = tile * TR;

    // ---- weights/biases (block-uniform address -> SGPR-resident) ----
    // ws rows: 0=maxgate 1=p0 2=p1 3=p2 4=p3 5=gate0 6=gate2(leaf1+node)
    float ws[7][9];
#pragma unroll
    for (int i = 0; i < 9; ++i) {
        ws[0][i] = maxgate[c * 9  + i];
        ws[1][i] = pconvs [c * 36 + i * 4 + 0];
        ws[2][i] = pconvs [c * 36 + i * 4 + 1];
        ws[3][i] = pconvs [c * 36 + i * 4 + 2];
        ws[4][i] = pconvs [c * 36 + i * 4 + 3];
        ws[5][i] = pgates [c * 27 + i * 3 + 0];
        ws[6][i] = pgates [c * 27 + i * 3 + 2];
    }
    const float bmax = mb[c];
    const float bp0 = pbs[c * 4 + 0], bp1 = pbs[c * 4 + 1];
    const float bp2 = pbs[c * 4 + 2], bp3 = pbs[c * 4 + 3];
    const float bg0 = gbs[c * 3 + 0];   // leaf0 gate bias
    const float bg1 = gbs[c * 3 + 1];   // leaf1 gate bias
    const float bg2 = gbs[c * 3 + 2];   // node gate bias

    const float* xplane = x + (size_t)plane * (HH * HH);

    // ---- async stage: input rows 2r0-3 .. 2r0+33 into xs, zero-pad at edges ----
    {
        const int ir0  = 2 * r0 - 3;
        const int lo   = ir0 < 0 ? 0 : ir0;
        const int hie  = ir0 + XR - 1;
        const int hi   = hie > HH - 1 ? HH - 1 : hie;
        const int ztop = lo - ir0;                 // 3 for tile 0, else 0
        const int zbot = hie - hi;                 // 2 for tile 3, else 0
        for (int i = t; i < ztop * HH; i += TB) (&xs[0][0])[i] = 0.f;
        for (int i = t; i < zbot * HH; i += TB) (&xs[XR - zbot][0])[i] = 0.f;
        const int    nfl  = (hi - lo + 1) * HH;    // multiple of 128
        const float* gsrc = xplane + lo * HH;
        float*       ldst = &xs[ztop][0];
        const int nchunk = nfl >> 8;               // 1KB chunks (64 lanes x 16B)
        for (int k = wv; k < nchunk; k += TB / 64)
            gl2lds16(gsrc + (k << 8) + lane * 4, ldst + (k << 8));
        if ((nfl & 255) && wv == 0) {              // 512B tail
            const int off = nchunk << 8;
            gl2lds4(gsrc + off + lane,      ldst + off);
            gl2lds4(gsrc + off + 64 + lane, ldst + off + 64);
        }
        // n0 side cols (gc = -1 and 64) are outside the image -> always 0
        if (t < 2 * (TR + 2)) n0s[t >> 1][(t & 1) ? 66 : 1] = 0.f;
    }
    __syncthreads();                               // slab + side zeros ready

    // ---- n0 halo rows (gr = r0-1, r0+TR; zero outside image) ----
    if (t < 132) {
        const int hb  = (t >= 66);                 // 0 top, 1 bottom
        const int cc2 = hb ? t - 66 : t;           // 0..65
        const int gc  = cc2 - 1;                   // out col -1..64
        const int gr  = hb ? r0 + TR : r0 - 1;
        float n0v = 0.f;
        if ((unsigned)gr < (unsigned)OHW && (unsigned)gc < (unsigned)OHW) {
            const int sb = hb ? 2 * TR + 2 : 0;    // slab row base
            float ag = 0.f, a0 = 0.f, a1 = 0.f;
#pragma unroll
            for (int dr = 0; dr < 3; ++dr) {
                const float* row = &xs[sb + dr][0];
                const float w0 = (gc > 0) ? row[2 * gc - 1] : 0.f;
                const float w1 = row[2 * gc];
                const float w2 = row[2 * gc + 1];
                ag += w0 * ws[5][3*dr] + w1 * ws[5][3*dr+1] + w2 * ws[5][3*dr+2];
                a0 += w0 * ws[1][3*dr] + w1 * ws[1][3*dr+1] + w2 * ws[1][3*dr+2];
                a1 += w0 * ws[2][3*dr] + w1 * ws[2][3*dr+1] + w2 * ws[2][3*dr+2];
            }
            const float sg = sigmoidf(ag + bg0);
            n0v = sg * (a0 + bp0) + (1.f - sg) * (a1 + bp1);
        }
        n0s[hb ? TR + 1 : 0][cc2 + 1] = n0v;
    }

    // ---- stage 1 interior: 2 cols x 1 row per micro-step, rows g0 & g0+8 ----
    const int p  = t & 31;             // col pair: out cols {2p, 2p+1}
    const int g0 = t >> 5;             // 0..7
    float out1[2][2], n1v[2][2];

#pragma unroll
    for (int k = 0; k < 2; ++k) {
        const int lr = g0 + 8 * k;
        const int gr = r0 + lr;
        float a[7][2];
#pragma unroll
        for (int ci = 0; ci < 7; ++ci) { a[ci][0] = 0.f; a[ci][1] = 0.f; }
        float mp0 = -INFINITY, mp1 = -INFINITY;
#pragma unroll
        for (int dr = 0; dr < 3; ++dr) {
            const float* row = &xs[2 * lr + 2 + dr][0];
            const float  v0 = (p > 0) ? row[4 * p - 1] : 0.f;
            const float4 vv = *reinterpret_cast<const float4*>(&row[4 * p]);
            const bool rowok = (gr > 0) | (dr > 0);
            const float h0 = fmaxf(fmaxf((p > 0) ? v0 : -INFINITY, vv.x), vv.y);
            const float h1 = fmaxf(fmaxf(vv.y, vv.z), vv.w);
            mp0 = fmaxf(mp0, rowok ? h0 : -INFINITY);
            mp1 = fmaxf(mp1, rowok ? h1 : -INFINITY);
#pragma unroll
            for (int ci = 0; ci < 7; ++ci) {
                a[ci][0] += v0   * ws[ci][3*dr] + vv.x * ws[ci][3*dr+1] + vv.y * ws[ci][3*dr+2];
                a[ci][1] += vv.y * ws[ci][3*dr] + vv.z * ws[ci][3*dr+1] + vv.w * ws[ci][3*dr+2];
            }
        }
        const float sg0a = sigmoidf(a[5][0] + bg0);
        const float sg0b = sigmoidf(a[5][1] + bg0);
        const float n0a = sg0a * (a[1][0] + bp0) + (1.f - sg0a) * (a[2][0] + bp1);
        const float n0b = sg0b * (a[1][1] + bp0) + (1.f - sg0b) * (a[2][1] + bp1);
        *reinterpret_cast<f32x2*>(&n0s[lr + 1][2 * p + 2]) = (f32x2){ n0a, n0b };
        const float sg1a = sigmoidf(a[6][0] + bg1);    // leaf1 gate: bias gbs[:,1]
        const float sg1b = sigmoidf(a[6][1] + bg1);
        n1v[k][0] = sg1a * (a[3][0] + bp2) + (1.f - sg1a) * (a[4][0] + bp3);
        n1v[k][1] = sg1b * (a[3][1] + bp2) + (1.f - sg1b) * (a[4][1] + bp3);
        out1[k][0] = mp0 * (a[0][0] + bmax);
        out1[k][1] = mp1 * (a[0][1] + bmax);
    }
    __syncthreads();

    // ---- stage 2: node gate conv on n0 (stride 1, pad 1) + combine + store ----
    float* oplane = out + (size_t)plane * (OHW * OHW);
#pragma unroll
    for (int k = 0; k < 2; ++k) {
        const int lr = g0 + 8 * k;
        float ag0 = 0.f, ag1 = 0.f, n0c0 = 0.f, n0c1 = 0.f;
#pragma unroll
        for (int dr = 0; dr < 3; ++dr) {
            const float e0  = n0s[lr + dr][2 * p + 1];
            const f32x2 mid = *reinterpret_cast<const f32x2*>(&n0s[lr + dr][2 * p + 2]);
            const float e3  = n0s[lr + dr][2 * p + 4];
            ag0 += e0    * ws[6][3*dr] + mid.x * ws[6][3*dr+1] + mid.y * ws[6][3*dr+2];
            ag1 += mid.x * ws[6][3*dr] + mid.y * ws[6][3*dr+1] + e3    * ws[6][3*dr+2];
            if (dr == 1) { n0c0 = mid.x; n0c1 = mid.y; }
        }
        const float ga = sigmoidf(ag0 + bg2);          // node gate: bias gbs[:,2]
        const float gb = sigmoidf(ag1 + bg2);
        f32x2 rv;
        rv.x = out1[k][0] + n0c0 * ga + n1v[k][0] * (1.f - ga);
        rv.y = out1[k][1] + n0c1 * gb + n1v[k][1] * (1.f - gb);
        __builtin_nontemporal_store(rv,
            reinterpret_cast<f32x2*>(oplane + (r0 + lr) * OHW + 2 * p));
    }
}

extern "C" void kernel_launch(void* const* d_in, const int* in_sizes, int n_in,
                              void* d_out, int out_size, void* d_ws, size_t ws_size,
                              hipStream_t stream) {
    const float* x       = (const float*)d_in[0];
    const float* maxgate = (const float*)d_in[1];
    const float* mb      = (const float*)d_in[2];
    const float* pconvs  = (const float*)d_in[3];
    const float* pbs     = (const float*)d_in[4];
    const float* pgates  = (const float*)d_in[5];
    const float* gbs     = (const float*)d_in[6];
    float* out           = (float*)d_out;

    fused_densenet_kernel<<<NBLK, TB, 0, stream>>>(
        x, maxgate, mb, pconvs, pbs, pgates, gbs, out);
}